// Round 8
// baseline (166.361 us; speedup 1.0000x reference)
//
#include <hip/hip_runtime.h>
#include <stdint.h>

// VQ: inputs (16,64,64,64) f32 BCHW, codebook (1024,64) f32.
// out[0:65536] = argmin indices as float; out[65536:] = gathered rows, BCHW.
//
// r8 = r7 (validated, spill-free) with occupancy doubled:
//  - 512 blocks x 512 thr (8 waves). Wave owns 16 positions (z frags in
//    16 VGPR, built from global). Each 32 KB codebook chunk staged once
//    serves 8 waves (r7: 4) -> half the staging/barrier cost per wave.
//  - LDS ~72 KB -> 2 blocks/CU = 16 waves/CU (~50% occ cap vs r7's 13%).
//  - launch_bounds(512,4) -> VGPR cap 128, design ~90 -> no spill.
//  - numerics unchanged (r4/r6/r7-validated): 3-pass bf16 hi/lo MFMA filter,
//    packed (s|k) keys, BIAS=0.25, DELTA=1e-4 gap -> exact rescreen with
//    bit-exact numpy pairwise znorm and t/u/d op order.
#define NUM_K 1024
#define CDIM  64
#define NPOS  65536
#define NPB   128
#define DELTA 1e-4f
#define BIAS  0.25f

typedef __attribute__((ext_vector_type(8))) short short8;
typedef __attribute__((ext_vector_type(4))) float f32x4;
typedef unsigned int u32;
typedef __attribute__((address_space(3))) u32 lds_u32;
typedef const __attribute__((address_space(1))) u32 g_u32;

union U4S8 { uint4 u; short8 s; };

// ---- d_ws layout (bytes) ----
#define WS_CNORM 0         // 1024 f32 exact
#define WS_CNB   4096      // 1024 f32 (cnorm + BIAS)
#define WS_CB    8192      // 8 chunks * 32768: per chunk hi 16384 | lo 16384
                           // row kl (0..127): byte kl*128 + ((s*16)^((kl&7)*16))

__device__ __forceinline__ void cvt_pair(float f0, float f1,
                                         uint32_t& hp, uint32_t& lp) {
    uint32_t h;
    asm("v_cvt_pk_bf16_f32 %0, %1, %2" : "=v"(h) : "v"(f0), "v"(f1));
    float h0 = __uint_as_float(h << 16);
    float h1 = __uint_as_float(h & 0xFFFF0000u);
    float r0 = f0 - h0, r1 = f1 - h1;
    uint32_t l;
    asm("v_cvt_pk_bf16_f32 %0, %1, %2" : "=v"(l) : "v"(r0), "v"(r1));
    hp = h; lp = l;
}

__device__ __forceinline__ unsigned long long shflxor64(unsigned long long v, int off) {
    unsigned lo = (unsigned)v, hi = (unsigned)(v >> 32);
    lo = (unsigned)__shfl_xor((int)lo, off);
    hi = (unsigned)__shfl_xor((int)hi, off);
    return ((unsigned long long)hi << 32) | lo;
}

__device__ __forceinline__ void gload_lds16(const void* g, void* l) {
    __builtin_amdgcn_global_load_lds((g_u32*)g, (lds_u32*)l, 16, 0, 0);
}

// ---- kernel 1: cnorm (exact pairwise) + pre-split swizzled bf16 hi/lo ----
__global__ __launch_bounds__(256) void vq_prep_kernel(
    const float* __restrict__ cb, unsigned char* __restrict__ ws) {
#pragma clang fp contract(off)
    const int k = blockIdx.x * 256 + threadIdx.x;   // grid = 4 blocks
    const float4* row4 = (const float4*)(cb + k * CDIM);
    float v[CDIM];
#pragma unroll
    for (int i = 0; i < 16; ++i) {
        float4 t = row4[i];
        v[i * 4 + 0] = t.x; v[i * 4 + 1] = t.y;
        v[i * 4 + 2] = t.z; v[i * 4 + 3] = t.w;
    }
    float r[8];
#pragma unroll
    for (int j = 0; j < 8; ++j) r[j] = v[j] * v[j];
#pragma unroll
    for (int i = 1; i < 8; ++i) {
#pragma unroll
        for (int j = 0; j < 8; ++j) {
            float s = v[i * 8 + j] * v[i * 8 + j];
            r[j] = r[j] + s;
        }
    }
    const float cn =
        ((r[0] + r[1]) + (r[2] + r[3])) + ((r[4] + r[5]) + (r[6] + r[7]));
    ((float*)(ws + WS_CNORM))[k] = cn;
    ((float*)(ws + WS_CNB))[k]   = cn + BIAS;

    const int c  = k >> 7, kl = k & 127;
    unsigned char* hi_base = ws + WS_CB + c * 32768;
    unsigned char* lo_base = hi_base + 16384;
#pragma unroll
    for (int s = 0; s < 8; ++s) {
        U4S8 H, L;
        uint32_t hp, lp;
        cvt_pair(v[s * 8 + 0], v[s * 8 + 1], hp, lp); H.u.x = hp; L.u.x = lp;
        cvt_pair(v[s * 8 + 2], v[s * 8 + 3], hp, lp); H.u.y = hp; L.u.y = lp;
        cvt_pair(v[s * 8 + 4], v[s * 8 + 5], hp, lp); H.u.z = hp; L.u.z = lp;
        cvt_pair(v[s * 8 + 6], v[s * 8 + 7], hp, lp); H.u.w = hp; L.u.w = lp;
        const int byte = kl * 128 + ((s * 16) ^ ((kl & 7) * 16));
        *(uint4*)(hi_base + byte) = H.u;
        *(uint4*)(lo_base + byte) = L.u;
    }
}

// ---- LDS layout (bytes) ----
#define LDS_BUF  0         // 2 bufs * 32768 (hi 16384 | lo 16384)
#define LDS_CNB  65536     // 1024 f32
#define LDS_SFIN 69632     // 128 int
#define LDS_AMBC 70144
#define LDS_AMBL 70148     // 128 int
#define LDS_ZSC  70672     // 8 waves * 64 f32 (16B aligned)
#define SMEM_SZ  72720

// ---- kernel 2: main ----
__global__ __launch_bounds__(512, 4) void vq_main_kernel(
    const float* __restrict__ in, const float* __restrict__ cb,
    const unsigned char* __restrict__ ws, float* __restrict__ out) {
#pragma clang fp contract(off)
    const int tid  = threadIdx.x;
    const int lane = tid & 63;
    const int wv   = tid >> 6;          // 0..7
    const int l15  = lane & 15;
    const int lg   = lane >> 4;         // 0..3
    const int n0g  = blockIdx.x * NPB;
    const int b    = n0g >> 12;
    const int hw0  = n0g & 4095;

    __shared__ __align__(16) unsigned char smem[SMEM_SZ];
    float* cnb_l   = (float*)(smem + LDS_CNB);
    int*   sfin    = (int*)(smem + LDS_SFIN);
    int*   ambcnt  = (int*)(smem + LDS_AMBC);
    int*   amblist = (int*)(smem + LDS_AMBL);
    float* zsc     = (float*)(smem + LDS_ZSC);
    const unsigned char* cbws = ws + WS_CB;
    const float* cnorm = (const float*)(ws + WS_CNORM);

    if (tid == 0) *ambcnt = 0;

    // ---- issue async stage of chunk 0 into buf0 (wave wv: 4 KB slice) ----
    {
        const unsigned char* src = cbws + wv * 4096 + lane * 16;
        unsigned char* dst = smem + LDS_BUF + wv * 4096;   // wave-uniform dst
#pragma unroll
        for (int i = 0; i < 4; ++i)
            gload_lds16(src + i * 1024, dst + i * 1024);
    }

    // ---- stage cnb into LDS (overlaps chunk-0 flight) ----
#pragma unroll
    for (int i = 0; i < 2; ++i)
        cnb_l[i * 512 + tid] = ((const float*)(ws + WS_CNB))[i * 512 + tid];

    // ---- z frags straight from global: wave owns pos wv*16..+15 ----
    short8 zfh[2], zfl[2];
    {
        const int pos = wv * 16 + l15;
#pragma unroll
        for (int ks = 0; ks < 2; ++ks) {
            const int sl = ks * 4 + lg;
            const float* zp = in + (((size_t)(b * CDIM + sl * 8)) << 12) + hw0 + pos;
            float f[8];
#pragma unroll
            for (int j = 0; j < 8; ++j) f[j] = zp[(size_t)j << 12];
            U4S8 H, L;
            uint32_t hp, lp;
            cvt_pair(f[0], f[1], hp, lp); H.u.x = hp; L.u.x = lp;
            cvt_pair(f[2], f[3], hp, lp); H.u.y = hp; L.u.y = lp;
            cvt_pair(f[4], f[5], hp, lp); H.u.z = hp; L.u.z = lp;
            cvt_pair(f[6], f[7], hp, lp); H.u.w = hp; L.u.w = lp;
            zfh[ks] = H.s; zfl[ks] = L.s;
        }
    }
    __syncthreads();    // chunk 0 + cnb ready

    const float finf = __uint_as_float(0x7F800000u);
    float m1 = finf, m2 = finf;

    int buf = 0;
    for (int c = 0; c < 8; ++c) {
        if (c < 7) {    // async stage next chunk into other buffer
            const unsigned char* src = cbws + (c + 1) * 32768 + wv * 4096 + lane * 16;
            unsigned char* dst = smem + LDS_BUF + (buf ^ 1) * 32768 + wv * 4096;
#pragma unroll
            for (int i = 0; i < 4; ++i)
                gload_lds16(src + i * 1024, dst + i * 1024);
        }

        const unsigned char* qb = smem + LDS_BUF + buf * 32768;
#pragma unroll
        for (int kt = 0; kt < 8; ++kt) {
            const int row = kt * 16 + l15;
            const int rsw = (row & 7) * 16;
            const int off0 = row * 128 + ((lg * 16) ^ rsw);
            const int off1 = row * 128 + (((4 + lg) * 16) ^ rsw);
            short8 ah0 = *(const short8*)(qb + off0);
            short8 al0 = *(const short8*)(qb + 16384 + off0);
            short8 ah1 = *(const short8*)(qb + off1);
            short8 al1 = *(const short8*)(qb + 16384 + off1);

            f32x4 acc = {0.f, 0.f, 0.f, 0.f};
            acc = __builtin_amdgcn_mfma_f32_16x16x32_bf16(al0, zfh[0], acc, 0, 0, 0);
            acc = __builtin_amdgcn_mfma_f32_16x16x32_bf16(ah0, zfl[0], acc, 0, 0, 0);
            acc = __builtin_amdgcn_mfma_f32_16x16x32_bf16(ah0, zfh[0], acc, 0, 0, 0);
            acc = __builtin_amdgcn_mfma_f32_16x16x32_bf16(al1, zfh[1], acc, 0, 0, 0);
            acc = __builtin_amdgcn_mfma_f32_16x16x32_bf16(ah1, zfl[1], acc, 0, 0, 0);
            acc = __builtin_amdgcn_mfma_f32_16x16x32_bf16(ah1, zfh[1], acc, 0, 0, 0);

            const int kb = c * 128 + kt * 16 + lg * 4;
            const f32x4 cn = *(const f32x4*)(cnb_l + kb);
#pragma unroll
            for (int r = 0; r < 4; ++r) {
                float s = fmaf(-2.0f, acc[r], cn[r]);
                float key = __uint_as_float(
                    (__float_as_uint(s) & 0xFFFFFC00u) | (uint32_t)(kb + r));
                m2 = fminf(m2, fmaxf(key, m1));
                m1 = fminf(m1, key);
            }
        }
        __syncthreads();    // next-chunk staging drained; buf free
        buf ^= 1;
    }

    // ---- merge the 4 k-lane-groups (lanes l15, +16, +32, +48) ----
#pragma unroll
    for (int off = 16; off <= 32; off <<= 1) {
        float o1 = __shfl_xor(m1, off);
        float o2 = __shfl_xor(m2, off);
        m2 = fminf(fminf(m2, o2), fmaxf(m1, o1));
        m1 = fminf(m1, o1);
    }

    // ---- finalize: lg==0 lanes own position wv*16+l15 ----
    if (lg == 0) {
        const int n = wv * 16 + l15;
        const uint32_t u1 = __float_as_uint(m1);
        const int idx = (int)(u1 & 1023u);
        sfin[n] = idx;
        out[n0g + n] = (float)idx;
        const float v1 = __uint_as_float(u1 & 0xFFFFFC00u);
        const float v2 = __uint_as_float(__float_as_uint(m2) & 0xFFFFFC00u);
        if (v2 - v1 < DELTA) {
            int p = atomicAdd(ambcnt, 1);
            amblist[p] = n;
        }
    }
    __syncthreads();

    // ---- exact rescreen, wave-parallel (validated numerics; z via LDS) ----
    const int namb = *ambcnt;
    for (int i = wv; i < namb; i += 8) {
        const int n = amblist[i];
        float zc = in[(((size_t)(b * CDIM + lane)) << 12) + hw0 + n];
        // bit-exact numpy pairwise znorm via shfl
        float sq = zc * zc;
        float accp = sq;
#pragma unroll
        for (int i2 = 1; i2 < 8; ++i2)
            accp = accp + __shfl(sq, i2 * 8 + (lane & 7));
        float t1 = accp + __shfl_xor(accp, 1);
        float t2 = t1 + __shfl_xor(t1, 2);
        float t3 = t2 + __shfl_xor(t2, 4);
        const float zn = __shfl(t3, 0);
        zsc[wv * 64 + lane] = zc;
        const float* zrow = &zsc[wv * 64];
        unsigned long long bestk = ~0ull;
        for (int j = 0; j < 16; ++j) {
            const int k = j * 64 + lane;
            const float4* e = (const float4*)(cb + (size_t)k * CDIM);
            float a0 = 0.f, a1 = 0.f, a2 = 0.f, a3 = 0.f;
#pragma unroll
            for (int i2 = 0; i2 < 4; ++i2) {
                float4 zz = *(const float4*)(zrow + i2 * 16);
                float4 z1 = *(const float4*)(zrow + i2 * 16 + 4);
                float4 z2 = *(const float4*)(zrow + i2 * 16 + 8);
                float4 z3 = *(const float4*)(zrow + i2 * 16 + 12);
                float4 v0 = e[i2 * 4 + 0];
                float4 v1 = e[i2 * 4 + 1];
                float4 v2 = e[i2 * 4 + 2];
                float4 v3 = e[i2 * 4 + 3];
                a0 = fmaf(zz.x, v0.x, a0); a0 = fmaf(zz.y, v0.y, a0);
                a0 = fmaf(zz.z, v0.z, a0); a0 = fmaf(zz.w, v0.w, a0);
                a1 = fmaf(z1.x, v1.x, a1); a1 = fmaf(z1.y, v1.y, a1);
                a1 = fmaf(z1.z, v1.z, a1); a1 = fmaf(z1.w, v1.w, a1);
                a2 = fmaf(z2.x, v2.x, a2); a2 = fmaf(z2.y, v2.y, a2);
                a2 = fmaf(z2.z, v2.z, a2); a2 = fmaf(z2.w, v2.w, a2);
                a3 = fmaf(z3.x, v3.x, a3); a3 = fmaf(z3.y, v3.y, a3);
                a3 = fmaf(z3.z, v3.z, a3); a3 = fmaf(z3.w, v3.w, a3);
            }
            float dot = (a0 + a1) + (a2 + a3);
            float t = zn + cnorm[k];   // fl(znorm + cnorm)
            float u = 2.0f * dot;      // fl(2*dot)
            float d = t - u;           // fl(t - u)
            unsigned long long key =
                ((unsigned long long)__float_as_uint(d) << 10) | (unsigned)k;
            bestk = key < bestk ? key : bestk;
        }
#pragma unroll
        for (int off = 32; off >= 1; off >>= 1) {
            unsigned long long o = shflxor64(bestk, off);
            bestk = o < bestk ? o : bestk;
        }
        if (lane == 0) {
            const int idx = (int)(bestk & 1023u);
            sfin[n] = idx;
            out[n0g + n] = (float)idx;
        }
    }
    __syncthreads();

    // ---- zqs epilogue: gather -> LDS tile [128][65] (overlay buf) ----
    float (*tile)[65] = (float (*)[65])(smem);
    {
        const int p = tid >> 2, q4 = tid & 3;   // p: 0..127
        const int idx = sfin[p];
        const float4* row = (const float4*)(cb + (size_t)idx * CDIM) + q4 * 4;
#pragma unroll
        for (int i = 0; i < 4; ++i) {
            float4 v = row[i];
            const int cch = q4 * 16 + i * 4;
            tile[p][cch + 0] = v.x; tile[p][cch + 1] = v.y;
            tile[p][cch + 2] = v.z; tile[p][cch + 3] = v.w;
        }
    }
    __syncthreads();
    {
        float* zq = out + NPOS + (((size_t)b * CDIM) << 12) + hw0;
#pragma unroll
        for (int i = 0; i < 8; ++i) {
            const int cch = i * 8 + wv;
#pragma unroll
            for (int h = 0; h < 2; ++h)
                zq[((size_t)cch << 12) + h * 64 + lane] = tile[h * 64 + lane][cch];
        }
    }
}

extern "C" void kernel_launch(void* const* d_in, const int* in_sizes, int n_in,
                              void* d_out, int out_size, void* d_ws, size_t ws_size,
                              hipStream_t stream) {
    const float* in = (const float*)d_in[0];   // 16*64*64*64
    const float* cb = (const float*)d_in[1];   // 1024*64
    float* out = (float*)d_out;                // 65536 + 4194304
    unsigned char* ws = (unsigned char*)d_ws;  // ~270 KB used

    vq_prep_kernel<<<NUM_K / 256, 256, 0, stream>>>(cb, ws);
    vq_main_kernel<<<NPOS / NPB, 512, 0, stream>>>(in, cb, ws, out);
}